// Round 4
// baseline (45.030 us; speedup 1.0000x reference)
//
#include <hip/hip_runtime.h>
#include <math.h>

#define TWO_PI_F 6.28318530717958647692f

typedef unsigned int u32;
typedef __attribute__((ext_vector_type(4))) u32      u32x4;
typedef __attribute__((ext_vector_type(4))) float    f4;
typedef __attribute__((ext_vector_type(2))) _Float16 h2;

union V8 { u32x4 v; h2 h[4]; };

// ---------------------------------------------------------------------------
// Kernel 1: per-index projections in f16, swizzled global layout.
//   A[i,h] = zc[h] + pe(s_i) @ W1[0:4, h]   (zc = b1 + z_g @ W1[10:42])
//   B[i,h] = pe(s_i) @ W1[4:8, h]
// Layout: X[i>>6][il][h ^ (((il>>2)&7)<<3)], il = i&63  (64-row blocks,
// h-contiguous f16) -> main kernel stages with a linear copy and reads
// conflict-free ds_read_b128 (8 h per read).
// ---------------------------------------------------------------------------
__global__ __launch_bounds__(256) void gd_precomp(
    const float* __restrict__ z,  const float* __restrict__ s,
    const float* __restrict__ W1, const float* __restrict__ b1,
    _Float16* __restrict__ A2, _Float16* __restrict__ B2,
    float* __restrict__ cs, float* __restrict__ sn, int N)
{
    __shared__ float zc[64];
    int t = threadIdx.x;
    if (t < 64) {
        float acc = b1[t];
#pragma unroll
        for (int zz = 0; zz < 32; ++zz)
            acc = fmaf(z[zz], W1[(10 + zz) * 64 + t], acc);
        zc[t] = acc;
    }
    __syncthreads();

    int gid = blockIdx.x * 256 + t;
    if (gid >= N * 64) return;
    int i = gid >> 6;
    int h = gid & 63;

    float sv  = s[i];
    float ang = TWO_PI_F * sv;
    float c1  = __cosf(ang);
    float s1  = __sinf(ang);
    float c2  = c1 * c1 - s1 * s1;   // exact double-angle for k=2
    float s2  = 2.0f * c1 * s1;

    float A = zc[h];
    A = fmaf(c1, W1[0 * 64 + h], A);
    A = fmaf(s1, W1[1 * 64 + h], A);
    A = fmaf(c2, W1[2 * 64 + h], A);
    A = fmaf(s2, W1[3 * 64 + h], A);

    float B = 0.0f;
    B = fmaf(c1, W1[4 * 64 + h], B);
    B = fmaf(s1, W1[5 * 64 + h], B);
    B = fmaf(c2, W1[6 * 64 + h], B);
    B = fmaf(s2, W1[7 * 64 + h], B);

    int blk = i >> 6;
    int il  = i & 63;
    int col = h ^ (((il >> 2) & 7) << 3);   // XOR swizzle in GLOBAL layout
    A2[blk * 4096 + il * 64 + col] = (_Float16)A;
    B2[blk * 4096 + il * 64 + col] = (_Float16)B;
    if (h == 0) { cs[i] = c1; sn[i] = s1; }
}

// ---------------------------------------------------------------------------
// Kernel 2: one 64x64 output tile per block, upper-triangular blocks only.
// 256 threads, each owns a 4x4 patch, computes BOTH orientations (shared
// diff term) in packed f16 (v_pk_fma_f16 / v_pk_max_f16), writes the
// symmetrized tile with float4 stores + mirrored tile via LDS transpose.
// ---------------------------------------------------------------------------
__global__ __launch_bounds__(256, 2) void gd_main(
    const _Float16* __restrict__ A2, const _Float16* __restrict__ B2,
    const float* __restrict__ cs,  const float* __restrict__ sn,
    const float* __restrict__ W1,  const float* __restrict__ W2,
    const float* __restrict__ b2v, float* __restrict__ out, int N, int NB)
{
    __shared__ __attribute__((aligned(16))) _Float16 sAB[4][64][64]; // Ai,Bi,Aj,Bj
    __shared__ __attribute__((aligned(16))) _Float16 sWc[64], sWs[64], sW2[64];
    __shared__ float csi[64], sni[64], csj[64], snj[64];

    // --- triangular block decode: u -> (bi, bj), bj >= bi ---
    int u = blockIdx.x;
    int M = 2 * NB + 1;
    float disc = (float)(M * M - 8 * u);
    int bi = (int)(((float)M - sqrtf(disc)) * 0.5f);
    if (bi < 0) bi = 0;
    if (bi > NB - 1) bi = NB - 1;
    while (bi > 0 && bi * (M - bi) / 2 > u) --bi;
    while ((bi + 1) * (M - (bi + 1)) / 2 <= u) ++bi;
    int bj = bi + (u - bi * (M - bi) / 2);

    int t = threadIdx.x;

    // --- staging: linear conflict-free copies (layout pre-swizzled) ---
    {
        const u32x4* g0 = (const u32x4*)(A2 + (size_t)bi * 4096);
        const u32x4* g1 = (const u32x4*)(B2 + (size_t)bi * 4096);
        const u32x4* g2 = (const u32x4*)(A2 + (size_t)bj * 4096);
        const u32x4* g3 = (const u32x4*)(B2 + (size_t)bj * 4096);
        u32x4* d = (u32x4*)&sAB[0][0][0];
        d[t]          = g0[t];
        d[t + 256]    = g0[t + 256];
        d[t + 512]    = g1[t];
        d[t + 768]    = g1[t + 256];
        d[t + 1024]   = g2[t];
        d[t + 1280]   = g2[t + 256];
        d[t + 1536]   = g3[t];
        d[t + 1792]   = g3[t + 256];
    }
    if (t < 64) {
        sWc[t] = (_Float16)W1[8 * 64 + t];
        sWs[t] = (_Float16)W1[9 * 64 + t];
        sW2[t] = (_Float16)(0.5f * W2[t]);   // fold the 0.5 symmetrization
        csi[t] = cs[bi * 64 + t];
        sni[t] = sn[bi * 64 + t];
        csj[t] = cs[bj * 64 + t];
        snj[t] = sn[bj * 64 + t];
    }
    __syncthreads();

    int tj4 = t & 15;
    int ti4 = t >> 4;

    // diff-term cos/sin per (row, col) pair, replicated into h2
    h2 ct2[4][4], st2[4][4];
#pragma unroll
    for (int r = 0; r < 4; ++r) {
        int il = ti4 * 4 + r;
        float ci = csi[il], si = sni[il];
#pragma unroll
        for (int c = 0; c < 4; ++c) {
            int jl = tj4 * 4 + c;
            float cj = csj[jl], sj = snj[jl];
            float ctf = fmaf(ci, cj, si * sj);                // cos(2pi*dist)
            float stf = fabsf(fmaf(si, cj, -(ci * sj)));      // sin(2pi*dist)
            _Float16 cth = (_Float16)ctf;
            _Float16 sth = (_Float16)stf;
            ct2[r][c] = (h2){cth, cth};
            st2[r][c] = (h2){sth, sth};
        }
    }

    h2 acc1[4][4], acc2[4][4];
#pragma unroll
    for (int r = 0; r < 4; ++r)
#pragma unroll
        for (int c = 0; c < 4; ++c) { acc1[r][c] = (h2)0; acc2[r][c] = (h2)0; }

    int rbase[4], rkey[4], cbase[4], ckey[4];
#pragma unroll
    for (int r = 0; r < 4; ++r) {
        int il = ti4 * 4 + r;
        rbase[r] = il * 64;
        rkey[r]  = ((il >> 2) & 7) << 3;
    }
#pragma unroll
    for (int c = 0; c < 4; ++c) {
        int jl = tj4 * 4 + c;
        cbase[c] = jl * 64;
        ckey[c]  = ((jl >> 2) & 7) << 3;
    }

    const _Float16* pAi = &sAB[0][0][0];
    const _Float16* pBi = &sAB[1][0][0];
    const _Float16* pAj = &sAB[2][0][0];
    const _Float16* pBj = &sAB[3][0][0];

#pragma unroll 2
    for (int hg = 0; hg < 8; ++hg) {
        int h0 = hg * 8;
        V8 wc8, ws8, w28;
        wc8.v = *(const u32x4*)&sWc[h0];
        ws8.v = *(const u32x4*)&sWs[h0];
        w28.v = *(const u32x4*)&sW2[h0];

        V8 ai8[4], bi8[4], aj8[4], bj8[4];
#pragma unroll
        for (int r = 0; r < 4; ++r) {
            ai8[r].v = *(const u32x4*)&pAi[rbase[r] + (h0 ^ rkey[r])];
            bi8[r].v = *(const u32x4*)&pBi[rbase[r] + (h0 ^ rkey[r])];
        }
#pragma unroll
        for (int c = 0; c < 4; ++c) {
            aj8[c].v = *(const u32x4*)&pAj[cbase[c] + (h0 ^ ckey[c])];
            bj8[c].v = *(const u32x4*)&pBj[cbase[c] + (h0 ^ ckey[c])];
        }

#pragma unroll
        for (int r = 0; r < 4; ++r) {
#pragma unroll
            for (int c = 0; c < 4; ++c) {
                h2 ct = ct2[r][c];
                h2 st = st2[r][c];
#pragma unroll
                for (int k = 0; k < 4; ++k) {
                    h2 d2 = __builtin_elementwise_fma(ct, wc8.h[k], st * ws8.h[k]);
                    h2 p1 = ai8[r].h[k] + bj8[c].h[k] + d2;   // orientation (i,j)
                    h2 p2 = aj8[c].h[k] + bi8[r].h[k] + d2;   // orientation (j,i)
                    acc1[r][c] = __builtin_elementwise_fma(
                        __builtin_elementwise_max(p1, (h2)0), w28.h[k], acc1[r][c]);
                    acc2[r][c] = __builtin_elementwise_fma(
                        __builtin_elementwise_max(p2, (h2)0), w28.h[k], acc2[r][c]);
                }
            }
        }
    }

    float b2 = b2v[0];
    float vals[4][4];
#pragma unroll
    for (int r = 0; r < 4; ++r) {
        int gi = bi * 64 + ti4 * 4 + r;
#pragma unroll
        for (int c = 0; c < 4; ++c) {
            int gj = bj * 64 + tj4 * 4 + c;
            float v = (float)acc1[r][c][0] + (float)acc1[r][c][1] +
                      (float)acc2[r][c][0] + (float)acc2[r][c][1] + b2;
            if (gi == gj) v = -1e9f;
            vals[r][c] = v;
        }
    }

    // direct (upper) tile: one float4 store per row
#pragma unroll
    for (int r = 0; r < 4; ++r) {
        int gi = bi * 64 + ti4 * 4 + r;
        f4 o = {vals[r][0], vals[r][1], vals[r][2], vals[r][3]};
        *(f4*)&out[(size_t)gi * N + bj * 64 + tj4 * 4] = o;
    }

    if (bj > bi) {   // mirrored block via LDS transpose (stride 67: 2-way max)
        __syncthreads();
        float* tile = (float*)&sAB[0][0][0];   // 64*67*4 = 17.2 KB < 32 KB
#pragma unroll
        for (int r = 0; r < 4; ++r)
#pragma unroll
            for (int c = 0; c < 4; ++c)
                tile[(ti4 * 4 + r) * 67 + tj4 * 4 + c] = vals[r][c];
        __syncthreads();
#pragma unroll
        for (int r = 0; r < 4; ++r) {
            int orow = ti4 * 4 + r;            // j-space row
            f4 m;
#pragma unroll
            for (int c = 0; c < 4; ++c)
                m[c] = tile[(tj4 * 4 + c) * 67 + orow];
            *(f4*)&out[(size_t)(bj * 64 + orow) * N + bi * 64 + tj4 * 4] = m;
        }
    }
}

extern "C" void kernel_launch(void* const* d_in, const int* in_sizes, int n_in,
                              void* d_out, int out_size, void* d_ws, size_t ws_size,
                              hipStream_t stream) {
    const float* z  = (const float*)d_in[0];  // [32]
    const float* s  = (const float*)d_in[1];  // [N]
    const float* W1 = (const float*)d_in[2];  // [42,64]
    const float* b1 = (const float*)d_in[3];  // [64]
    const float* W2 = (const float*)d_in[4];  // [64]
    const float* b2 = (const float*)d_in[5];  // [1]
    int N = in_sizes[1];                      // 2048

    _Float16* A2 = (_Float16*)d_ws;               // N*64 f16 (swizzled)
    _Float16* B2 = A2 + (size_t)N * 64;           // N*64 f16 (swizzled)
    float*    cs = (float*)(B2 + (size_t)N * 64); // N f32
    float*    sn = cs + N;                        // N f32

    float* out = (float*)d_out;

    gd_precomp<<<(N * 64 + 255) / 256, 256, 0, stream>>>(
        z, s, W1, b1, A2, B2, cs, sn, N);

    int NB = N / 64;
    int nblk = NB * (NB + 1) / 2;
    gd_main<<<nblk, 256, 0, stream>>>(A2, B2, cs, sn, W1, W2, b2, out, N, NB);
}

// Round 5
// 44.703 us; speedup vs baseline: 1.0073x; 1.0073x over previous
//
#include <hip/hip_runtime.h>
#include <math.h>

#define TWO_PI_F 6.28318530717958647692f

typedef unsigned int u32;
typedef __attribute__((ext_vector_type(4))) u32      u32x4;
typedef __attribute__((ext_vector_type(4))) float    f4;
typedef __attribute__((ext_vector_type(2))) _Float16 h2;

union V8 { u32x4 v; h2 h[4]; };

// padded row: 72 f16 (144 B) -> LDS bank stride 4, conflict-free b128 reads
// with ZERO per-read address math (base reg + compile-time immediate).
#define ROWP 72
#define BLKF (64 * ROWP)   // 4608 f16 per 64-row block

// ---------------------------------------------------------------------------
// Kernel 1: per-index projections in f16, padded global layout.
//   A[i,h] = zc[h] + pe(s_i) @ W1[0:4, h]   (zc = b1 + z_g @ W1[10:42])
//   B[i,h] = pe(s_i) @ W1[4:8, h]
// Layout: X[i>>6][il][h] with row pitch ROWP=72 f16. cs/sn = cos/sin(2*pi*s).
// ---------------------------------------------------------------------------
__global__ __launch_bounds__(256) void gd_precomp(
    const float* __restrict__ z,  const float* __restrict__ s,
    const float* __restrict__ W1, const float* __restrict__ b1,
    _Float16* __restrict__ A2, _Float16* __restrict__ B2,
    float* __restrict__ cs, float* __restrict__ sn, int N)
{
    __shared__ float zc[64];
    int t = threadIdx.x;
    if (t < 64) {
        float acc = b1[t];
#pragma unroll
        for (int zz = 0; zz < 32; ++zz)
            acc = fmaf(z[zz], W1[(10 + zz) * 64 + t], acc);
        zc[t] = acc;
    }
    __syncthreads();

    int gid = blockIdx.x * 256 + t;
    if (gid >= N * 64) return;
    int i = gid >> 6;
    int h = gid & 63;

    float sv  = s[i];
    float ang = TWO_PI_F * sv;
    float c1  = __cosf(ang);
    float s1  = __sinf(ang);
    float c2  = c1 * c1 - s1 * s1;   // exact double-angle for k=2
    float s2  = 2.0f * c1 * s1;

    float A = zc[h];
    A = fmaf(c1, W1[0 * 64 + h], A);
    A = fmaf(s1, W1[1 * 64 + h], A);
    A = fmaf(c2, W1[2 * 64 + h], A);
    A = fmaf(s2, W1[3 * 64 + h], A);

    float B = 0.0f;
    B = fmaf(c1, W1[4 * 64 + h], B);
    B = fmaf(s1, W1[5 * 64 + h], B);
    B = fmaf(c2, W1[6 * 64 + h], B);
    B = fmaf(s2, W1[7 * 64 + h], B);

    int blk = i >> 6;
    int il  = i & 63;
    A2[blk * BLKF + il * ROWP + h] = (_Float16)A;
    B2[blk * BLKF + il * ROWP + h] = (_Float16)B;
    if (h == 0) { cs[i] = c1; sn[i] = s1; }
}

// ---------------------------------------------------------------------------
// Kernel 2: one 64x64 output tile per block, upper-triangular blocks only.
// 512 threads, each owns a 2x4 patch (rows 2*ti2..+1, cols 4*tj4..+3),
// computes BOTH orientations (shared diff term) in packed f16, writes the
// symmetrized tile with float4 stores + mirrored tile via LDS transpose.
// ---------------------------------------------------------------------------
__global__ __launch_bounds__(512, 4) void gd_main(
    const _Float16* __restrict__ A2, const _Float16* __restrict__ B2,
    const float* __restrict__ cs,  const float* __restrict__ sn,
    const float* __restrict__ W1,  const float* __restrict__ W2,
    const float* __restrict__ b2v, float* __restrict__ out, int N, int NB)
{
    __shared__ __attribute__((aligned(16))) _Float16 sAB[4][64][ROWP]; // 36864 B
    __shared__ __attribute__((aligned(16))) _Float16 sWc[64], sWs[64], sW2[64];
    __shared__ float csi[64], sni[64], csj[64], snj[64];

    // --- triangular block decode: u -> (bi, bj), bj >= bi ---
    int u = blockIdx.x;
    int M = 2 * NB + 1;
    float disc = (float)(M * M - 8 * u);
    int bi = (int)(((float)M - sqrtf(disc)) * 0.5f);
    if (bi < 0) bi = 0;
    if (bi > NB - 1) bi = NB - 1;
    while (bi > 0 && bi * (M - bi) / 2 > u) --bi;
    while ((bi + 1) * (M - (bi + 1)) / 2 <= u) ++bi;
    int bj = bi + (u - bi * (M - bi) / 2);

    int t = threadIdx.x;

    // --- staging: linear copies, 576 u32x4 chunks per array section ---
    {
        const _Float16* srcs[4] = { A2 + (size_t)bi * BLKF, B2 + (size_t)bi * BLKF,
                                    A2 + (size_t)bj * BLKF, B2 + (size_t)bj * BLKF };
        u32x4* d = (u32x4*)&sAB[0][0][0];
#pragma unroll
        for (int a = 0; a < 4; ++a) {
            const u32x4* g = (const u32x4*)srcs[a];
            d[a * 576 + t] = g[t];
            if (t < 64) d[a * 576 + 512 + t] = g[512 + t];
        }
    }
    if (t < 64) {
        sWc[t] = (_Float16)W1[8 * 64 + t];
        sWs[t] = (_Float16)W1[9 * 64 + t];
        sW2[t] = (_Float16)(0.5f * W2[t]);   // fold the 0.5 symmetrization
        csi[t] = cs[bi * 64 + t];
        sni[t] = sn[bi * 64 + t];
        csj[t] = cs[bj * 64 + t];
        snj[t] = sn[bj * 64 + t];
    }
    __syncthreads();

    int tj4 = t & 15;    // 16 col-quads
    int ti2 = t >> 4;    // 32 row-pairs

    // diff-term cos/sin per (row, col) pair, replicated into h2
    h2 ct2[2][4], st2[2][4];
#pragma unroll
    for (int r = 0; r < 2; ++r) {
        int il = ti2 * 2 + r;
        float ci = csi[il], si = sni[il];
#pragma unroll
        for (int c = 0; c < 4; ++c) {
            int jl = tj4 * 4 + c;
            float cj = csj[jl], sj = snj[jl];
            float ctf = fmaf(ci, cj, si * sj);                // cos(2pi*dist)
            float stf = fabsf(fmaf(si, cj, -(ci * sj)));      // sin(2pi*dist)
            _Float16 cth = (_Float16)ctf;
            _Float16 sth = (_Float16)stf;
            ct2[r][c] = (h2){cth, cth};
            st2[r][c] = (h2){sth, sth};
        }
    }

    h2 acc1[2][4], acc2[2][4];
#pragma unroll
    for (int r = 0; r < 2; ++r)
#pragma unroll
        for (int c = 0; c < 4; ++c) { acc1[r][c] = (h2)0; acc2[r][c] = (h2)0; }

#pragma unroll
    for (int hg = 0; hg < 8; ++hg) {
        const int h0 = hg * 8;
        V8 wc8, ws8, w28;
        wc8.v = *(const u32x4*)&sWc[h0];        // uniform addr -> broadcast
        ws8.v = *(const u32x4*)&sWs[h0];
        w28.v = *(const u32x4*)&sW2[h0];

        V8 ai8[2], bi8[2], aj8[4], bj8[4];
#pragma unroll
        for (int r = 0; r < 2; ++r) {
            int il = ti2 * 2 + r;
            ai8[r].v = *(const u32x4*)&sAB[0][il][h0];  // base + imm offset
            bi8[r].v = *(const u32x4*)&sAB[1][il][h0];
        }
#pragma unroll
        for (int c = 0; c < 4; ++c) {
            int jl = tj4 * 4 + c;
            aj8[c].v = *(const u32x4*)&sAB[2][jl][h0];
            bj8[c].v = *(const u32x4*)&sAB[3][jl][h0];
        }

#pragma unroll
        for (int r = 0; r < 2; ++r) {
#pragma unroll
            for (int c = 0; c < 4; ++c) {
                h2 ct = ct2[r][c];
                h2 st = st2[r][c];
#pragma unroll
                for (int k = 0; k < 4; ++k) {
                    h2 d2 = __builtin_elementwise_fma(ct, wc8.h[k], st * ws8.h[k]);
                    h2 p1 = ai8[r].h[k] + bj8[c].h[k] + d2;   // orientation (i,j)
                    h2 p2 = aj8[c].h[k] + bi8[r].h[k] + d2;   // orientation (j,i)
                    acc1[r][c] = __builtin_elementwise_fma(
                        __builtin_elementwise_max(p1, (h2)0), w28.h[k], acc1[r][c]);
                    acc2[r][c] = __builtin_elementwise_fma(
                        __builtin_elementwise_max(p2, (h2)0), w28.h[k], acc2[r][c]);
                }
            }
        }
    }

    float b2 = b2v[0];
    float vals[2][4];
#pragma unroll
    for (int r = 0; r < 2; ++r) {
        int gi = bi * 64 + ti2 * 2 + r;
#pragma unroll
        for (int c = 0; c < 4; ++c) {
            int gj = bj * 64 + tj4 * 4 + c;
            float v = (float)acc1[r][c][0] + (float)acc1[r][c][1] +
                      (float)acc2[r][c][0] + (float)acc2[r][c][1] + b2;
            if (gi == gj) v = -1e9f;
            vals[r][c] = v;
        }
    }

    // direct (upper) tile: one float4 store per row
#pragma unroll
    for (int r = 0; r < 2; ++r) {
        int gi = bi * 64 + ti2 * 2 + r;
        f4 o = {vals[r][0], vals[r][1], vals[r][2], vals[r][3]};
        *(f4*)&out[(size_t)gi * N + bj * 64 + tj4 * 4] = o;
    }

    if (bj > bi) {   // mirrored block via LDS transpose (stride 67)
        __syncthreads();
        float* tile = (float*)&sAB[0][0][0];   // 64*67*4 = 17.2 KB < 36.8 KB
#pragma unroll
        for (int r = 0; r < 2; ++r)
#pragma unroll
            for (int c = 0; c < 4; ++c)
                tile[(ti2 * 2 + r) * 67 + tj4 * 4 + c] = vals[r][c];
        __syncthreads();
#pragma unroll
        for (int r = 0; r < 2; ++r) {
            int orow = ti2 * 2 + r;            // j-space row
            f4 m;
#pragma unroll
            for (int c = 0; c < 4; ++c)
                m[c] = tile[(tj4 * 4 + c) * 67 + orow];
            *(f4*)&out[(size_t)(bj * 64 + orow) * N + bi * 64 + tj4 * 4] = m;
        }
    }
}

extern "C" void kernel_launch(void* const* d_in, const int* in_sizes, int n_in,
                              void* d_out, int out_size, void* d_ws, size_t ws_size,
                              hipStream_t stream) {
    const float* z  = (const float*)d_in[0];  // [32]
    const float* s  = (const float*)d_in[1];  // [N]
    const float* W1 = (const float*)d_in[2];  // [42,64]
    const float* b1 = (const float*)d_in[3];  // [64]
    const float* W2 = (const float*)d_in[4];  // [64]
    const float* b2 = (const float*)d_in[5];  // [1]
    int N = in_sizes[1];                      // 2048

    int NB = N / 64;
    size_t blkElems = (size_t)NB * BLKF;          // padded f16 per array
    _Float16* A2 = (_Float16*)d_ws;
    _Float16* B2 = A2 + blkElems;
    float*    cs = (float*)(B2 + blkElems);
    float*    sn = cs + N;

    float* out = (float*)d_out;

    gd_precomp<<<(N * 64 + 255) / 256, 256, 0, stream>>>(
        z, s, W1, b1, A2, B2, cs, sn, N);

    int nblk = NB * (NB + 1) / 2;
    gd_main<<<nblk, 512, 0, stream>>>(A2, B2, cs, sn, W1, W2, b2, out, N, NB);
}

// Round 6
// 42.329 us; speedup vs baseline: 1.0638x; 1.0561x over previous
//
#include <hip/hip_runtime.h>
#include <math.h>

#define TWO_PI_F 6.28318530717958647692f

typedef unsigned int u32;
typedef __attribute__((ext_vector_type(4))) u32      u32x4;
typedef __attribute__((ext_vector_type(4))) float    f4;
typedef __attribute__((ext_vector_type(2))) _Float16 h2;

union V8 { u32x4 v; h2 h[4]; };

// ---------------------------------------------------------------------------
// Fully fused kernel: one 64x64 output tile per block, upper-triangular
// blocks only. Each block regenerates its own A/B projections directly into
// LDS (no precomp kernel, no workspace traffic):
//   A[r,h] = zc[h] + pe(s_r) @ W1[0:4,h]   (zc = b1 + z @ W1[10:42])
//   B[r,h] = pe(s_r) @ W1[4:8,h]
// LDS layout: sAB[arr][row][h ^ (((row>>2)&7)<<3)]  -> all hot ds ops <=2-way.
// 512 threads; compute phase: each thread owns a 2x4 patch, evaluates BOTH
// orientations (shared diff term) in packed f16, writes symmetrized tile
// (float4) + mirrored tile via LDS transpose.
// ---------------------------------------------------------------------------
__global__ __launch_bounds__(512, 4) void gd_fused(
    const float* __restrict__ z,  const float* __restrict__ s,
    const float* __restrict__ W1, const float* __restrict__ b1,
    const float* __restrict__ W2, const float* __restrict__ b2v,
    float* __restrict__ out, int N, int NB)
{
    __shared__ __attribute__((aligned(16))) _Float16 sAB[4][64][64]; // Ai,Bi,Aj,Bj
    __shared__ __attribute__((aligned(16))) _Float16 sWc[64], sWs[64], sW2[64];
    __shared__ float strig[4][128];   // c1,s1,c2,s2 per local row (0:63=i, 64:127=j)
    __shared__ float zc[64];

    // --- triangular block decode: u -> (bi, bj), bj >= bi ---
    int u = blockIdx.x;
    int M = 2 * NB + 1;
    float disc = (float)(M * M - 8 * u);
    int bi = (int)(((float)M - sqrtf(disc)) * 0.5f);
    if (bi < 0) bi = 0;
    if (bi > NB - 1) bi = NB - 1;
    while (bi > 0 && bi * (M - bi) / 2 > u) --bi;
    while ((bi + 1) * (M - (bi + 1)) / 2 <= u) ++bi;
    int bj = bi + (u - bi * (M - bi) / 2);

    int t = threadIdx.x;

    // --- setup phase: disjoint thread ranges, one barrier ---
    if (t < 64) {                       // zc = b1 + z @ W1[10:42]
        float acc = b1[t];
#pragma unroll
        for (int zz = 0; zz < 32; ++zz)
            acc = fmaf(z[zz], W1[(10 + zz) * 64 + t], acc);
        zc[t] = acc;
    } else if (t < 128) {               // diff weights + W2 (0.5 folded)
        int h = t - 64;
        sWc[h] = (_Float16)W1[8 * 64 + h];
        sWs[h] = (_Float16)W1[9 * 64 + h];
        sW2[h] = (_Float16)(0.5f * W2[h]);
    } else if (t < 256) {               // per-row trig
        int r = t - 128;
        int grow = (r < 64) ? (bi * 64 + r) : (bj * 64 + (r - 64));
        float ang = TWO_PI_F * s[grow];
        float c1 = __cosf(ang);
        float s1 = __sinf(ang);
        strig[0][r] = c1;
        strig[1][r] = s1;
        strig[2][r] = c1 * c1 - s1 * s1;   // exact double-angle k=2
        strig[3][r] = 2.0f * c1 * s1;
    }
    __syncthreads();

    // --- phase 1: generate A/B projections into LDS ---
    {
        int h  = t & 63;
        int rg = t >> 6;                 // 8 row-groups x 16 rows
        float w1v[8];
#pragma unroll
        for (int w = 0; w < 8; ++w) w1v[w] = W1[w * 64 + h];
        float zch = zc[h];
#pragma unroll
        for (int rr = 0; rr < 16; ++rr) {
            int row = rg * 16 + rr;
            float c1 = strig[0][row], s1 = strig[1][row];
            float c2 = strig[2][row], s2 = strig[3][row];
            float A = zch;
            A = fmaf(c1, w1v[0], A);
            A = fmaf(s1, w1v[1], A);
            A = fmaf(c2, w1v[2], A);
            A = fmaf(s2, w1v[3], A);
            float B = c1 * w1v[4];
            B = fmaf(s1, w1v[5], B);
            B = fmaf(c2, w1v[6], B);
            B = fmaf(s2, w1v[7], B);
            int arr = (row >> 6) * 2;    // 0: i-rows, 2: j-rows
            int lr  = row & 63;
            int col = h ^ (((lr >> 2) & 7) << 3);
            sAB[arr + 0][lr][col] = (_Float16)A;
            sAB[arr + 1][lr][col] = (_Float16)B;
        }
    }
    __syncthreads();

    // --- phase 2: 2x4 patch per thread, packed f16 ---
    int tj4 = t & 15;
    int ti2 = t >> 4;

    h2 ct2[2][4], st2[2][4];
#pragma unroll
    for (int r = 0; r < 2; ++r) {
        int il = ti2 * 2 + r;
        float ci = strig[0][il], si = strig[1][il];
#pragma unroll
        for (int c = 0; c < 4; ++c) {
            int jl = tj4 * 4 + c;
            float cj = strig[0][64 + jl], sj = strig[1][64 + jl];
            float ctf = fmaf(ci, cj, si * sj);              // cos(2pi*dist)
            float stf = fabsf(fmaf(si, cj, -(ci * sj)));    // sin(2pi*dist)
            _Float16 cth = (_Float16)ctf;
            _Float16 sth = (_Float16)stf;
            ct2[r][c] = (h2){cth, cth};
            st2[r][c] = (h2){sth, sth};
        }
    }

    h2 acc1[2][4], acc2[2][4];
#pragma unroll
    for (int r = 0; r < 2; ++r)
#pragma unroll
        for (int c = 0; c < 4; ++c) { acc1[r][c] = (h2)0; acc2[r][c] = (h2)0; }

    int rbase[2], rkey[2], cbase[4], ckey[4];
#pragma unroll
    for (int r = 0; r < 2; ++r) {
        int il = ti2 * 2 + r;
        rbase[r] = il * 64;
        rkey[r]  = ((il >> 2) & 7) << 3;
    }
#pragma unroll
    for (int c = 0; c < 4; ++c) {
        int jl = tj4 * 4 + c;
        cbase[c] = jl * 64;
        ckey[c]  = ((jl >> 2) & 7) << 3;
    }

    const _Float16* pAi = &sAB[0][0][0];
    const _Float16* pBi = &sAB[1][0][0];
    const _Float16* pAj = &sAB[2][0][0];
    const _Float16* pBj = &sAB[3][0][0];

#pragma unroll
    for (int hg = 0; hg < 8; ++hg) {
        const int h0 = hg * 8;
        V8 wc8, ws8, w28;
        wc8.v = *(const u32x4*)&sWc[h0];        // uniform addr -> broadcast
        ws8.v = *(const u32x4*)&sWs[h0];
        w28.v = *(const u32x4*)&sW2[h0];

        V8 ai8[2], bi8[2], aj8[4], bj8[4];
#pragma unroll
        for (int r = 0; r < 2; ++r) {
            ai8[r].v = *(const u32x4*)&pAi[rbase[r] + (h0 ^ rkey[r])];
            bi8[r].v = *(const u32x4*)&pBi[rbase[r] + (h0 ^ rkey[r])];
        }
#pragma unroll
        for (int c = 0; c < 4; ++c) {
            aj8[c].v = *(const u32x4*)&pAj[cbase[c] + (h0 ^ ckey[c])];
            bj8[c].v = *(const u32x4*)&pBj[cbase[c] + (h0 ^ ckey[c])];
        }

#pragma unroll
        for (int r = 0; r < 2; ++r) {
#pragma unroll
            for (int c = 0; c < 4; ++c) {
                h2 ct = ct2[r][c];
                h2 st = st2[r][c];
#pragma unroll
                for (int k = 0; k < 4; ++k) {
                    h2 d2 = __builtin_elementwise_fma(ct, wc8.h[k], st * ws8.h[k]);
                    h2 p1 = ai8[r].h[k] + bj8[c].h[k] + d2;   // orientation (i,j)
                    h2 p2 = aj8[c].h[k] + bi8[r].h[k] + d2;   // orientation (j,i)
                    acc1[r][c] = __builtin_elementwise_fma(
                        __builtin_elementwise_max(p1, (h2)0), w28.h[k], acc1[r][c]);
                    acc2[r][c] = __builtin_elementwise_fma(
                        __builtin_elementwise_max(p2, (h2)0), w28.h[k], acc2[r][c]);
                }
            }
        }
    }

    float b2 = b2v[0];
    float vals[2][4];
#pragma unroll
    for (int r = 0; r < 2; ++r) {
        int gi = bi * 64 + ti2 * 2 + r;
#pragma unroll
        for (int c = 0; c < 4; ++c) {
            int gj = bj * 64 + tj4 * 4 + c;
            float v = (float)acc1[r][c][0] + (float)acc1[r][c][1] +
                      (float)acc2[r][c][0] + (float)acc2[r][c][1] + b2;
            if (gi == gj) v = -1e9f;
            vals[r][c] = v;
        }
    }

    // direct (upper) tile: one float4 store per row
#pragma unroll
    for (int r = 0; r < 2; ++r) {
        int gi = bi * 64 + ti2 * 2 + r;
        f4 o = {vals[r][0], vals[r][1], vals[r][2], vals[r][3]};
        *(f4*)&out[(size_t)gi * N + bj * 64 + tj4 * 4] = o;
    }

    if (bj > bi) {   // mirrored block via LDS transpose (stride 67)
        __syncthreads();
        float* tile = (float*)&sAB[0][0][0];   // 64*67*4 = 17.2 KB < 32.8 KB
#pragma unroll
        for (int r = 0; r < 2; ++r)
#pragma unroll
            for (int c = 0; c < 4; ++c)
                tile[(ti2 * 2 + r) * 67 + tj4 * 4 + c] = vals[r][c];
        __syncthreads();
#pragma unroll
        for (int r = 0; r < 2; ++r) {
            int orow = ti2 * 2 + r;            // j-space row
            f4 m;
#pragma unroll
            for (int c = 0; c < 4; ++c)
                m[c] = tile[(tj4 * 4 + c) * 67 + orow];
            *(f4*)&out[(size_t)(bj * 64 + orow) * N + bi * 64 + tj4 * 4] = m;
        }
    }
}

extern "C" void kernel_launch(void* const* d_in, const int* in_sizes, int n_in,
                              void* d_out, int out_size, void* d_ws, size_t ws_size,
                              hipStream_t stream) {
    const float* z  = (const float*)d_in[0];  // [32]
    const float* s  = (const float*)d_in[1];  // [N]
    const float* W1 = (const float*)d_in[2];  // [42,64]
    const float* b1 = (const float*)d_in[3];  // [64]
    const float* W2 = (const float*)d_in[4];  // [64]
    const float* b2 = (const float*)d_in[5];  // [1]
    int N = in_sizes[1];                      // 2048

    float* out = (float*)d_out;
    int NB = N / 64;
    int nblk = NB * (NB + 1) / 2;
    gd_fused<<<nblk, 512, 0, stream>>>(z, s, W1, b1, W2, b2, out, N, NB);
}